// Round 4
// baseline (309.705 us; speedup 1.0000x reference)
//
#include <hip/hip_runtime.h>
#include <math.h>

#define B_ 64
#define L_ 1024
#define D_ 64
#define NQT 16

typedef float4 f4;
typedef __attribute__((ext_vector_type(8))) short bf16x8;
typedef __attribute__((ext_vector_type(4))) float f32x4;

#define MFMA16(a, b, c) __builtin_amdgcn_mfma_f32_16x16x32_bf16(a, b, c, 0, 0, 0)
#define EXP2(x) __builtin_amdgcn_exp2f(x)
#define SWZ(row, off) ((off) ^ ((((row) ^ ((row) >> 3)) & 7) << 4))
#define SCL 0.18033688011112042f       // log2(e) / TEMP

// ws layout (bf16 packed operands)
#define KB_OFF 0u
#define QB_OFF (8u << 20)
#define VT_OFF (16u << 20)
#define ER_OFF (24u << 20)
#define WS_REQ ((24u << 20) + 131072u)

__device__ __forceinline__ ushort f2bf(float x) {
    unsigned u = __float_as_uint(x);
    return (ushort)((u + 0x7FFFu + ((u >> 16) & 1u)) >> 16);
}

// ---------------------------------------------------------------------------
// Prepack: Q,K,Er -> bf16 row-major; V -> bf16 transposed [b][d][l]
// ---------------------------------------------------------------------------
__global__ __launch_bounds__(256) void pack_lin(
    const float* __restrict__ Q, const float* __restrict__ K,
    const float* __restrict__ Er, char* __restrict__ ws)
{
    const int NQ = B_ * L_ * D_ / 4;          // 1048576 f4 groups per tensor
    const int NE = L_ * D_ / 4;
    ushort4* Qb = (ushort4*)(ws + QB_OFF);
    ushort4* Kb = (ushort4*)(ws + KB_OFF);
    ushort4* Eb = (ushort4*)(ws + ER_OFF);
    for (int i = blockIdx.x * 256 + threadIdx.x; i < 2 * NQ + NE;
         i += gridDim.x * 256) {
        const f4* src; ushort4* dst; int j;
        if (i < NQ)            { src = (const f4*)Q;  dst = Qb; j = i; }
        else if (i < 2 * NQ)   { src = (const f4*)K;  dst = Kb; j = i - NQ; }
        else                   { src = (const f4*)Er; dst = Eb; j = i - 2 * NQ; }
        f4 v = src[j];
        dst[j] = make_ushort4(f2bf(v.x), f2bf(v.y), f2bf(v.z), f2bf(v.w));
    }
}

__global__ __launch_bounds__(256) void pack_vt(
    const float* __restrict__ V, char* __restrict__ ws)
{
    __shared__ float sT[64][68];
    ushort* VT = (ushort*)(ws + VT_OFF);
    const int lt = blockIdx.x, b = blockIdx.y;
    const int l0 = lt * 64;
    const int r = threadIdx.x >> 4, c4 = threadIdx.x & 15;
#pragma unroll
    for (int i = 0; i < 4; ++i) {
        int row = r + 16 * i;
        f4 v = *(const f4*)(V + ((size_t)b * L_ + l0 + row) * D_ + 4 * c4);
        sT[row][4 * c4 + 0] = v.x; sT[row][4 * c4 + 1] = v.y;
        sT[row][4 * c4 + 2] = v.z; sT[row][4 * c4 + 3] = v.w;
    }
    __syncthreads();
    const int d = threadIdx.x >> 2, seg = threadIdx.x & 3;
    ushort tmp[16];
#pragma unroll
    for (int j = 0; j < 16; ++j) tmp[j] = f2bf(sT[seg * 16 + j][d]);
    ushort* dst = VT + ((size_t)b * D_ + d) * L_ + l0 + seg * 16;
#pragma unroll
    for (int j = 0; j < 4; ++j) *(ushort4*)(dst + 4 * j) = *(ushort4*)(tmp + 4 * j);
}

// ---------------------------------------------------------------------------
// Fused flash-style kernel, packed operands, fixed-max softmax.
// Phase A: row sums of 2^(score*SCL). Phase B: recompute, write probs, PV.
// ---------------------------------------------------------------------------
__global__ __launch_bounds__(256, 3) void fused_packed(
    const char* __restrict__ ws, float* __restrict__ Pout, float* __restrict__ O)
{
    __shared__ __align__(16) float sRT[128][68];   // skew scratch, [t][qi]
    __shared__ __align__(16) char  sPb[64 * 128];  // P tile bf16, swizzled
    __shared__ float sSt[64 * 4];
    __shared__ float sInv[64];

    const ushort* Kb = (const ushort*)(ws + KB_OFF);
    const ushort* Qb = (const ushort*)(ws + QB_OFF);
    const ushort* VT = (const ushort*)(ws + VT_OFF);
    const ushort* Eb = (const ushort*)(ws + ER_OFF);

    const int tid = threadIdx.x;
    const int b = blockIdx.x;
    const int qt = 15 - (int)blockIdx.y;           // heavy strips first
    const int q0 = qt * 64;
    const int lane = tid & 63, w = tid >> 6;
    const int fr = lane & 15, fc = lane >> 4;
    const int c4 = tid & 15, rsub = tid >> 4;
    const int lb = (L_ - 64) - q0;                 // Er row = lb + k0 + t

    // Q fragments: registers for the whole kernel
    bf16x8 qf[4][2];
#pragma unroll
    for (int rt = 0; rt < 4; ++rt)
#pragma unroll
        for (int kc = 0; kc < 2; ++kc)
            qf[rt][kc] = *(const bf16x8*)(Qb + ((size_t)b * L_ + q0 + 16 * rt + fr) * D_ +
                                          kc * 32 + fc * 8);

    auto loadK = [&](int k0, bf16x8* kf) {
#pragma unroll
        for (int kc = 0; kc < 2; ++kc)
            kf[kc] = *(const bf16x8*)(Kb + ((size_t)b * L_ + k0 + 16 * w + fr) * D_ +
                                      kc * 32 + fc * 8);
    };
    auto loadE = [&](int k0, bf16x8 (*ef)[2]) {
#pragma unroll
        for (int c = 0; c < 2; ++c) {
            int l = lb + k0 + (2 * w + c) * 16 + fr;
            if (l > L_ - 1) l = L_ - 1;            // clamp: masked entries only
#pragma unroll
            for (int kc = 0; kc < 2; ++kc)
                ef[c][kc] = *(const bf16x8*)(Eb + (size_t)l * D_ + kc * 32 + fc * 8);
        }
    };
    auto loadV = [&](int k0, bf16x8* vf) {
#pragma unroll
        for (int kc = 0; kc < 2; ++kc)
            vf[kc] = *(const bf16x8*)(VT + ((size_t)b * D_ + 16 * w + fr) * L_ + k0 +
                                      kc * 32 + fc * 8);
    };

    float sloc[16];
#pragma unroll
    for (int i = 0; i < 16; ++i) sloc[i] = 0.0f;

    bf16x8 kf[2], ef[2][2];
    loadK(0, kf); loadE(0, ef);

    // ================= PHASE A: row sums =================
    for (int kt = 0; kt <= qt; ++kt) {
        f32x4 accC[4] = {};
        f32x4 accR[4][2] = {};
#pragma unroll
        for (int rt = 0; rt < 4; ++rt)
#pragma unroll
            for (int kc = 0; kc < 2; ++kc) {
                accC[rt]    = MFMA16(qf[rt][kc], kf[kc],    accC[rt]);
                accR[rt][0] = MFMA16(qf[rt][kc], ef[0][kc], accR[rt][0]);
                accR[rt][1] = MFMA16(qf[rt][kc], ef[1][kc], accR[rt][1]);
            }
        { // prefetch next tile (same regs: written after last use)
            int kn = kt < qt ? kt + 1 : kt;
            loadK(64 * kn, kf); loadE(64 * kn, ef);
        }
        __syncthreads();                            // WAR: prev gather done
#pragma unroll
        for (int rt = 0; rt < 4; ++rt)
#pragma unroll
            for (int c = 0; c < 2; ++c)
                *(f4*)&sRT[(2 * w + c) * 16 + fr][16 * rt + 4 * fc] = *(f4*)&accR[rt][c];
        __syncthreads();
        const bool diag = (kt == qt);
#pragma unroll
        for (int rt = 0; rt < 4; ++rt)
#pragma unroll
            for (int r = 0; r < 4; ++r) {
                int qi = 16 * rt + 4 * fc + r;
                int kj = 16 * w + fr;
                float v = (accC[rt][r] + sRT[kj - qi + 63][qi]) * SCL;
                if (!(diag && kj > qi)) sloc[rt * 4 + r] += EXP2(v);
            }
    }

    // ---- row-sum reduce: butterfly over fr lanes, then across waves ----
#pragma unroll
    for (int off = 1; off <= 8; off <<= 1)
#pragma unroll
        for (int i = 0; i < 16; ++i) sloc[i] += __shfl_xor(sloc[i], off, 64);
    if (fr == 0)
#pragma unroll
        for (int i = 0; i < 16; ++i)
            sSt[(16 * (i >> 2) + 4 * fc + (i & 3)) * 4 + w] = sloc[i];
    __syncthreads();
    if (tid < 64)
        sInv[tid] = 1.0f / (sSt[tid * 4] + sSt[tid * 4 + 1] +
                            sSt[tid * 4 + 2] + sSt[tid * 4 + 3]);
    __syncthreads();
    float inv[16];
#pragma unroll
    for (int i = 0; i < 16; ++i) inv[i] = sInv[16 * (i >> 2) + 4 * fc + (i & 3)];

    // ================= PHASE B: probs + PV =================
    f32x4 accO[4] = {};
    bf16x8 vf[2];
    loadK(0, kf); loadE(0, ef);
    for (int kt = 0; kt <= qt; ++kt) {
        const int k0 = 64 * kt;
        loadV(k0, vf);                              // used late; full-body overlap
        f32x4 accC[4] = {};
        f32x4 accR[4][2] = {};
#pragma unroll
        for (int rt = 0; rt < 4; ++rt)
#pragma unroll
            for (int kc = 0; kc < 2; ++kc) {
                accC[rt]    = MFMA16(qf[rt][kc], kf[kc],    accC[rt]);
                accR[rt][0] = MFMA16(qf[rt][kc], ef[0][kc], accR[rt][0]);
                accR[rt][1] = MFMA16(qf[rt][kc], ef[1][kc], accR[rt][1]);
            }
        {
            int kn = kt < qt ? kt + 1 : kt;
            loadK(64 * kn, kf); loadE(64 * kn, ef);
        }
        __syncthreads();                 // WAR: prev gather + prev pa reads done
#pragma unroll
        for (int rt = 0; rt < 4; ++rt)
#pragma unroll
            for (int c = 0; c < 2; ++c)
                *(f4*)&sRT[(2 * w + c) * 16 + fr][16 * rt + 4 * fc] = *(f4*)&accR[rt][c];
        __syncthreads();
        const bool diag = (kt == qt);
#pragma unroll
        for (int rt = 0; rt < 4; ++rt)
#pragma unroll
            for (int r = 0; r < 4; ++r) {
                int qi = 16 * rt + 4 * fc + r;
                int kj = 16 * w + fr;
                float v = (accC[rt][r] + sRT[kj - qi + 63][qi]) * SCL;
                float p = (diag && kj > qi) ? 0.0f : EXP2(v) * inv[rt * 4 + r];
                Pout[((size_t)b * L_ + q0 + qi) * L_ + k0 + kj] = p;
                *(ushort*)(sPb + qi * 128 + SWZ(qi, 2 * kj)) = f2bf(p);
            }
        __syncthreads();
#pragma unroll
        for (int rt = 0; rt < 4; ++rt)
#pragma unroll
            for (int kc = 0; kc < 2; ++kc) {
                bf16x8 pa = *(const bf16x8*)(sPb + (16 * rt + fr) * 128 +
                                             SWZ(16 * rt + fr, kc * 64 + fc * 16));
                accO[rt] = MFMA16(pa, vf[kc], accO[rt]);
            }
    }

    // ---- zeros for the untouched upper region ----
    const int nz4 = 16 * (15 - qt);
    const f4 z = {0.0f, 0.0f, 0.0f, 0.0f};
#pragma unroll
    for (int i = 0; i < 4; ++i) {
        int row = rsub + 16 * i;
        float* base = Pout + ((size_t)b * L_ + q0 + row) * L_ + 64 * (qt + 1);
        for (int c = c4; c < nz4; c += 16) *(f4*)(base + 4 * c) = z;
    }
    // ---- O epilogue ----
#pragma unroll
    for (int rt = 0; rt < 4; ++rt)
#pragma unroll
        for (int rr = 0; rr < 4; ++rr)
            O[((size_t)b * L_ + q0 + rt * 16 + fc * 4 + rr) * D_ + 16 * w + fr] =
                accO[rt][rr];
}

// ---------------------------------------------------------------------------
// Legacy fallback (R3, proven): used only if ws_size < WS_REQ.
// ---------------------------------------------------------------------------
__global__ __launch_bounds__(256, 2) void fused_attn_legacy(
    const float* __restrict__ Q, const float* __restrict__ Kp,
    const float* __restrict__ V, const float* __restrict__ Er,
    float* __restrict__ Pout, float* __restrict__ O)
{
    __shared__ __align__(16) char sLDS[70144];
    ushort* sQ = (ushort*)sLDS;
    ushort* sK = (ushort*)(sLDS + 9216);
    ushort* sE = (ushort*)(sLDS + 18432);
    float*  sR = (float*)(sLDS + 36864);
    float*  sStat = (float*)sLDS;
    char*   sPb = sLDS + 18432;
    char*   sVb = sLDS + 18432 + 8192;

    const int tid = threadIdx.x;
    const int b  = blockIdx.x;
    const int qt = 15 - (int)blockIdx.y;
    const int q0 = qt * 64;
    const int c4 = tid & 15, rsub = tid >> 4;
    const int lane = tid & 63, w = tid >> 6;
    const int fr = lane & 15, fc = lane >> 4;
    const int l_base0 = (L_ - 64) - q0;

#pragma unroll
    for (int i = 0; i < 4; ++i) {
        int row = rsub + 16 * i;
        f4 qv = *(const f4*)(Q + ((size_t)b * L_ + q0 + row) * D_ + 4 * c4);
        *(ushort4*)(sQ + row * 72 + 4 * c4) =
            make_ushort4(f2bf(qv.x), f2bf(qv.y), f2bf(qv.z), f2bf(qv.w));
    }
    __syncthreads();
    bf16x8 qf[4][2];
#pragma unroll
    for (int rt = 0; rt < 4; ++rt)
#pragma unroll
        for (int kc = 0; kc < 2; ++kc)
            qf[rt][kc] = *(const bf16x8*)(sQ + (rt * 16 + fr) * 72 + kc * 32 + fc * 8);

    float mloc[16], sloc[16];
#pragma unroll
    for (int i = 0; i < 16; ++i) { mloc[i] = -1e30f; sloc[i] = 0.0f; }

    for (int kt = 0; kt <= qt; ++kt) {
        const int k0 = kt * 64;
        __syncthreads();
#pragma unroll
        for (int i = 0; i < 4; ++i) {
            int row = rsub + 16 * i;
            f4 kv = *(const f4*)(Kp + ((size_t)b * L_ + k0 + row) * D_ + 4 * c4);
            *(ushort4*)(sK + row * 72 + 4 * c4) =
                make_ushort4(f2bf(kv.x), f2bf(kv.y), f2bf(kv.z), f2bf(kv.w));
        }
#pragma unroll
        for (int i = 0; i < 8; ++i) {
            int trow = rsub + 16 * i;
            int l = l_base0 + k0 + trow;
            if (l > L_ - 1) l = L_ - 1;
            f4 ev = *(const f4*)(Er + (size_t)l * D_ + 4 * c4);
            *(ushort4*)(sE + trow * 72 + 4 * c4) =
                make_ushort4(f2bf(ev.x), f2bf(ev.y), f2bf(ev.z), f2bf(ev.w));
        }
        __syncthreads();
        bf16x8 kf[2], ef[2][2];
#pragma unroll
        for (int kc = 0; kc < 2; ++kc)
            kf[kc] = *(const bf16x8*)(sK + (16 * w + fr) * 72 + kc * 32 + fc * 8);
#pragma unroll
        for (int c = 0; c < 2; ++c)
#pragma unroll
            for (int kc = 0; kc < 2; ++kc)
                ef[c][kc] = *(const bf16x8*)(sE + ((2 * w + c) * 16 + fr) * 72 + kc * 32 + fc * 8);
        f32x4 accC[4] = {};
        f32x4 accR[4][2] = {};
#pragma unroll
        for (int rt = 0; rt < 4; ++rt)
#pragma unroll
            for (int kc = 0; kc < 2; ++kc) {
                accC[rt]    = MFMA16(qf[rt][kc], kf[kc],    accC[rt]);
                accR[rt][0] = MFMA16(qf[rt][kc], ef[0][kc], accR[rt][0]);
                accR[rt][1] = MFMA16(qf[rt][kc], ef[1][kc], accR[rt][1]);
            }
#pragma unroll
        for (int rt = 0; rt < 4; ++rt)
#pragma unroll
            for (int c = 0; c < 2; ++c)
#pragma unroll
                for (int r = 0; r < 4; ++r)
                    sR[(rt * 16 + fc * 4 + r) * 130 + (2 * w + c) * 16 + fr] = accR[rt][c][r];
        __syncthreads();
        const bool diag = (kt == qt);
#pragma unroll
        for (int rt = 0; rt < 4; ++rt)
#pragma unroll
            for (int r = 0; r < 4; ++r) {
                const int qi = rt * 16 + fc * 4 + r;
                const int kj = 16 * w + fr;
                float rel = sR[qi * 130 + kj - qi + 63];
                float v = (accC[rt][r] + rel) * SCL;
                if (!(diag && kj > qi)) {
                    const int idx = rt * 4 + r;
                    float mn = fmaxf(mloc[idx], v);
                    sloc[idx] = sloc[idx] * EXP2(mloc[idx] - mn) + EXP2(v - mn);
                    mloc[idx] = mn;
                }
            }
    }
#pragma unroll
    for (int off = 1; off <= 8; off <<= 1)
#pragma unroll
        for (int i = 0; i < 16; ++i) {
            float mo = __shfl_xor(mloc[i], off, 64);
            float so = __shfl_xor(sloc[i], off, 64);
            float mn = fmaxf(mloc[i], mo);
            sloc[i] = sloc[i] * EXP2(mloc[i] - mn) + so * EXP2(mo - mn);
            mloc[i] = mn;
        }
    __syncthreads();
    if (fr == 0) {
#pragma unroll
        for (int i = 0; i < 16; ++i) {
            int row = (i >> 2) * 16 + fc * 4 + (i & 3);
            ((float2*)sStat)[row * 4 + w] = make_float2(mloc[i], sloc[i]);
        }
    }
    __syncthreads();
    if (tid < 64) {
        float2 p0 = ((float2*)sStat)[tid * 4 + 0];
        float2 p1 = ((float2*)sStat)[tid * 4 + 1];
        float2 p2 = ((float2*)sStat)[tid * 4 + 2];
        float2 p3 = ((float2*)sStat)[tid * 4 + 3];
        float m = fmaxf(fmaxf(p0.x, p1.x), fmaxf(p2.x, p3.x));
        float s = p0.y * EXP2(p0.x - m) + p1.y * EXP2(p1.x - m) +
                  p2.y * EXP2(p2.x - m) + p3.y * EXP2(p3.x - m);
        ((float2*)(sStat + 512))[tid] = make_float2(m, 1.0f / s);
    }
    __syncthreads();
#pragma unroll
    for (int i = 0; i < 16; ++i) {
        int row = (i >> 2) * 16 + fc * 4 + (i & 3);
        float2 f = ((float2*)(sStat + 512))[row];
        mloc[i] = f.x; sloc[i] = f.y;
    }
    f32x4 accO[4] = {};
    for (int kt = 0; kt <= qt; ++kt) {
        const int k0 = kt * 64;
        __syncthreads();
        f4 vv[4];
#pragma unroll
        for (int j = 0; j < 4; ++j)
            vv[j] = *(const f4*)(V + ((size_t)b * L_ + k0 + 4 * rsub + j) * D_ + 4 * c4);
#pragma unroll
        for (int i = 0; i < 4; ++i) {
            int row = rsub + 16 * i;
            f4 kv = *(const f4*)(Kp + ((size_t)b * L_ + k0 + row) * D_ + 4 * c4);
            *(ushort4*)(sK + row * 72 + 4 * c4) =
                make_ushort4(f2bf(kv.x), f2bf(kv.y), f2bf(kv.z), f2bf(kv.w));
        }
#pragma unroll
        for (int i = 0; i < 8; ++i) {
            int trow = rsub + 16 * i;
            int l = l_base0 + k0 + trow;
            if (l > L_ - 1) l = L_ - 1;
            f4 ev = *(const f4*)(Er + (size_t)l * D_ + 4 * c4);
            *(ushort4*)(sE + trow * 72 + 4 * c4) =
                make_ushort4(f2bf(ev.x), f2bf(ev.y), f2bf(ev.z), f2bf(ev.w));
        }
        __syncthreads();
        bf16x8 kf[2], ef[2][2];
#pragma unroll
        for (int kc = 0; kc < 2; ++kc)
            kf[kc] = *(const bf16x8*)(sK + (16 * w + fr) * 72 + kc * 32 + fc * 8);
#pragma unroll
        for (int c = 0; c < 2; ++c)
#pragma unroll
            for (int kc = 0; kc < 2; ++kc)
                ef[c][kc] = *(const bf16x8*)(sE + ((2 * w + c) * 16 + fr) * 72 + kc * 32 + fc * 8);
        f32x4 accC[4] = {};
        f32x4 accR[4][2] = {};
#pragma unroll
        for (int rt = 0; rt < 4; ++rt)
#pragma unroll
            for (int kc = 0; kc < 2; ++kc) {
                accC[rt]    = MFMA16(qf[rt][kc], kf[kc],    accC[rt]);
                accR[rt][0] = MFMA16(qf[rt][kc], ef[0][kc], accR[rt][0]);
                accR[rt][1] = MFMA16(qf[rt][kc], ef[1][kc], accR[rt][1]);
            }
#pragma unroll
        for (int rt = 0; rt < 4; ++rt)
#pragma unroll
            for (int c = 0; c < 2; ++c)
#pragma unroll
                for (int r = 0; r < 4; ++r)
                    sR[(rt * 16 + fc * 4 + r) * 130 + (2 * w + c) * 16 + fr] = accR[rt][c][r];
        __syncthreads();
        const bool diag = (kt == qt);
#pragma unroll
        for (int rt = 0; rt < 4; ++rt)
#pragma unroll
            for (int r = 0; r < 4; ++r) {
                const int qi = rt * 16 + fc * 4 + r;
                const int kj = 16 * w + fr;
                float rel = sR[qi * 130 + kj - qi + 63];
                float v = (accC[rt][r] + rel) * SCL;
                const int idx = rt * 4 + r;
                float p = (diag && kj > qi) ? 0.0f : EXP2(v - mloc[idx]) * sloc[idx];
                Pout[((size_t)b * L_ + q0 + qi) * L_ + k0 + kj] = p;
                *(ushort*)(sPb + qi * 128 + SWZ(qi, 2 * kj)) = f2bf(p);
            }
#pragma unroll
        for (int dj = 0; dj < 4; ++dj) {
            int rowd = 4 * c4 + dj;
            float e0 = (&vv[0].x)[dj], e1 = (&vv[1].x)[dj],
                  e2 = (&vv[2].x)[dj], e3 = (&vv[3].x)[dj];
            *(ushort4*)(sVb + rowd * 128 + SWZ(rowd, 8 * rsub)) =
                make_ushort4(f2bf(e0), f2bf(e1), f2bf(e2), f2bf(e3));
        }
        __syncthreads();
        bf16x8 vf[2];
#pragma unroll
        for (int kc = 0; kc < 2; ++kc)
            vf[kc] = *(const bf16x8*)(sVb + (16 * w + fr) * 128 +
                                      SWZ(16 * w + fr, kc * 64 + fc * 16));
#pragma unroll
        for (int rt = 0; rt < 4; ++rt)
#pragma unroll
            for (int kc = 0; kc < 2; ++kc) {
                bf16x8 pa = *(const bf16x8*)(sPb + (rt * 16 + fr) * 128 +
                                             SWZ(rt * 16 + fr, kc * 64 + fc * 16));
                accO[rt] = MFMA16(pa, vf[kc], accO[rt]);
            }
    }
    const int nz4 = 16 * (15 - qt);
    const f4 z = {0.0f, 0.0f, 0.0f, 0.0f};
#pragma unroll
    for (int i = 0; i < 4; ++i) {
        int row = rsub + 16 * i;
        float* base = Pout + ((size_t)b * L_ + q0 + row) * L_ + 64 * (qt + 1);
        for (int c = c4; c < nz4; c += 16) *(f4*)(base + 4 * c) = z;
    }
#pragma unroll
    for (int rt = 0; rt < 4; ++rt)
#pragma unroll
        for (int rr = 0; rr < 4; ++rr)
            O[((size_t)b * L_ + q0 + rt * 16 + fc * 4 + rr) * D_ + 16 * w + fr] =
                accO[rt][rr];
}

// ---------------------------------------------------------------------------
extern "C" void kernel_launch(void* const* d_in, const int* in_sizes, int n_in,
                              void* d_out, int out_size, void* d_ws, size_t ws_size,
                              hipStream_t stream)
{
    const float* Q  = (const float*)d_in[0];
    const float* K  = (const float*)d_in[1];
    const float* V  = (const float*)d_in[2];
    const float* Er = (const float*)d_in[3];

    float* Out  = (float*)d_out;                          // [B, L, D]
    float* Attn = (float*)d_out + (size_t)B_ * L_ * D_;   // [B, L, L] probs

    if (ws_size >= (size_t)WS_REQ) {
        pack_lin<<<4096, 256, 0, stream>>>(Q, K, Er, (char*)d_ws);
        pack_vt<<<dim3(16, B_), 256, 0, stream>>>(V, (char*)d_ws);
        fused_packed<<<dim3(B_, NQT), 256, 0, stream>>>((const char*)d_ws, Attn, Out);
    } else {
        fused_attn_legacy<<<dim3(B_, NQT), 256, 0, stream>>>(Q, K, V, Er, Attn, Out);
    }
}

// Round 5
// 210.427 us; speedup vs baseline: 1.4718x; 1.4718x over previous
//
#include <hip/hip_runtime.h>
#include <math.h>

#define B_ 64
#define L_ 1024
#define D_ 64
#define NQT 16

typedef float4 f4;
typedef __attribute__((ext_vector_type(8))) short bf16x8;
typedef __attribute__((ext_vector_type(4))) float f32x4;

#define MFMA16(a, b, c) __builtin_amdgcn_mfma_f32_16x16x32_bf16(a, b, c, 0, 0, 0)
#define EXP2(x) __builtin_amdgcn_exp2f(x)
#define SWZ(row, off) ((off) ^ ((((row) ^ ((row) >> 3)) & 7) << 4))
#define SCL 0.18033688011112042f       // log2(e) / TEMP

// ws layout (bf16 packed operands)
#define KB_OFF 0u
#define QB_OFF (8u << 20)
#define VT_OFF (16u << 20)
#define ER_OFF (24u << 20)

__device__ __forceinline__ ushort f2bf(float x) {
    unsigned u = __float_as_uint(x);
    return (ushort)((u + 0x7FFFu + ((u >> 16) & 1u)) >> 16);
}

// ---------------------------------------------------------------------------
// Prepack: Q,K,Er -> bf16 row-major; V -> bf16 transposed [b][d][l]
// ---------------------------------------------------------------------------
__global__ __launch_bounds__(256) void pack_lin(
    const float* __restrict__ Q, const float* __restrict__ K,
    const float* __restrict__ Er, char* __restrict__ ws)
{
    const int NQ = B_ * L_ * D_ / 4;
    const int NE = L_ * D_ / 4;
    ushort4* Qb = (ushort4*)(ws + QB_OFF);
    ushort4* Kb = (ushort4*)(ws + KB_OFF);
    ushort4* Eb = (ushort4*)(ws + ER_OFF);
    for (int i = blockIdx.x * 256 + threadIdx.x; i < 2 * NQ + NE;
         i += gridDim.x * 256) {
        const f4* src; ushort4* dst; int j;
        if (i < NQ)          { src = (const f4*)Q;  dst = Qb; j = i; }
        else if (i < 2 * NQ) { src = (const f4*)K;  dst = Kb; j = i - NQ; }
        else                 { src = (const f4*)Er; dst = Eb; j = i - 2 * NQ; }
        f4 v = src[j];
        dst[j] = make_ushort4(f2bf(v.x), f2bf(v.y), f2bf(v.z), f2bf(v.w));
    }
}

__global__ __launch_bounds__(256) void pack_vt(
    const float* __restrict__ V, char* __restrict__ ws)
{
    __shared__ float sT[64][68];
    ushort* VT = (ushort*)(ws + VT_OFF);
    const int lt = blockIdx.x, b = blockIdx.y;
    const int l0 = lt * 64;
    const int r = threadIdx.x >> 4, c4 = threadIdx.x & 15;
#pragma unroll
    for (int i = 0; i < 4; ++i) {
        int row = r + 16 * i;
        f4 v = *(const f4*)(V + ((size_t)b * L_ + l0 + row) * D_ + 4 * c4);
        sT[row][4 * c4 + 0] = v.x; sT[row][4 * c4 + 1] = v.y;
        sT[row][4 * c4 + 2] = v.z; sT[row][4 * c4 + 3] = v.w;
    }
    __syncthreads();
    const int d = threadIdx.x >> 2, seg = threadIdx.x & 3;
    ushort tmp[16];
#pragma unroll
    for (int j = 0; j < 16; ++j) tmp[j] = f2bf(sT[seg * 16 + j][d]);
    ushort* dst = VT + ((size_t)b * D_ + d) * L_ + l0 + seg * 16;
#pragma unroll
    for (int j = 0; j < 4; ++j) *(ushort4*)(dst + 4 * j) = *(ushort4*)(tmp + 4 * j);
}

// ---------------------------------------------------------------------------
// Fused kernel: R3 staging structure (coalesced -> padded LDS -> fragments)
// with prepacked bf16 operands (zero hot-loop f2bf on K/E/V) and fixed-max
// softmax. Issue-early/write-late staging: next tile's global loads are
// issued during this tile's MFMAs.
// ---------------------------------------------------------------------------
__global__ __launch_bounds__(256, 2) void fused_v5(
    const char* __restrict__ ws, float* __restrict__ Pout, float* __restrict__ O)
{
    __shared__ __align__(16) ushort sK[64 * 72];    //  9216 B
    __shared__ __align__(16) ushort sE[128 * 72];   // 18432 B
    __shared__ __align__(16) ushort sV[64 * 72];    //  9216 B (aliased: stats)
    __shared__ __align__(16) float  sR[64 * 130];   // 33280 B skew scratch
    __shared__ __align__(16) char   sPb[64 * 128];  //  8192 B P bf16 swz

    float* sSt  = (float*)sV;          // [64][4] partial sums (phase gap only)
    float* sInv = (float*)sV + 256;    // [64]

    const int tid = threadIdx.x;
    const int b = blockIdx.x;
    const int qt = 15 - (int)blockIdx.y;            // heavy strips first
    const int q0 = qt * 64;
    const int lane = tid & 63, w = tid >> 6;
    const int fr = lane & 15, fc = lane >> 4;
    const int c4 = tid & 15, rsub = tid >> 4;
    const int t8 = tid >> 3, s8 = tid & 7;          // copy row / 16B slot
    const int lb = (L_ - 64) - q0;

    const ushort* Kb = (const ushort*)(ws + KB_OFF) + (size_t)b * L_ * D_;
    const ushort* Qb = (const ushort*)(ws + QB_OFF) + (size_t)b * L_ * D_;
    const ushort* VT = (const ushort*)(ws + VT_OFF) + (size_t)b * D_ * L_;
    const ushort* Eb = (const ushort*)(ws + ER_OFF);

    // Q fragments: registers for the whole kernel (one-time global read)
    bf16x8 qf[4][2];
#pragma unroll
    for (int rt = 0; rt < 4; ++rt)
#pragma unroll
        for (int kc = 0; kc < 2; ++kc)
            qf[rt][kc] = *(const bf16x8*)(Qb + (q0 + 16 * rt + fr) * D_ + kc * 32 + fc * 8);

    // ---- staging helpers: coalesced 16B chunks, reg round-trip ----
    auto ldK = [&](int k0, int4* r) {
        r[0] = *(const int4*)(Kb + (size_t)k0 * D_ + tid * 8);
        r[1] = *(const int4*)(Kb + (size_t)k0 * D_ + 2048 + tid * 8);
    };
    auto wrK = [&](const int4* r) {
        *(int4*)(sK + t8 * 72 + s8 * 8)        = r[0];
        *(int4*)(sK + (t8 + 32) * 72 + s8 * 8) = r[1];
    };
    auto ldE = [&](int k0, int4* r) {
#pragma unroll
        for (int j = 0; j < 4; ++j) {
            int row = t8 + 32 * j;
            int l = lb + k0 + row;
            if (l > L_ - 1) l = L_ - 1;             // clamp: masked entries only
            r[j] = *(const int4*)(Eb + (size_t)l * D_ + s8 * 8);
        }
    };
    auto wrE = [&](const int4* r) {
#pragma unroll
        for (int j = 0; j < 4; ++j)
            *(int4*)(sE + (t8 + 32 * j) * 72 + s8 * 8) = r[j];
    };
    auto ldV = [&](int k0, int4* r) {
#pragma unroll
        for (int j = 0; j < 2; ++j)
            r[j] = *(const int4*)(VT + (size_t)(t8 + 32 * j) * L_ + k0 + s8 * 8);
    };
    auto wrV = [&](const int4* r) {
#pragma unroll
        for (int j = 0; j < 2; ++j)
            *(int4*)(sV + (t8 + 32 * j) * 72 + s8 * 8) = r[j];
    };

    float sloc[16];
#pragma unroll
    for (int i = 0; i < 16; ++i) sloc[i] = 0.0f;

    int4 kreg[2], ereg[4], vreg[2];
    ldK(0, kreg); ldE(0, ereg);

    // ================= PHASE A: row sums of 2^(score*log2e) =================
    for (int kt = 0; kt <= qt; ++kt) {
        __syncthreads();                            // prev frag reads + gather done
        wrK(kreg); wrE(ereg);
        __syncthreads();
        bf16x8 kf[2], ef[2][2];
#pragma unroll
        for (int kc = 0; kc < 2; ++kc)
            kf[kc] = *(const bf16x8*)(sK + (16 * w + fr) * 72 + kc * 32 + fc * 8);
#pragma unroll
        for (int c = 0; c < 2; ++c)
#pragma unroll
            for (int kc = 0; kc < 2; ++kc)
                ef[c][kc] = *(const bf16x8*)(sE + ((2 * w + c) * 16 + fr) * 72 + kc * 32 + fc * 8);
        if (kt < qt) { ldK(64 * (kt + 1), kreg); ldE(64 * (kt + 1), ereg); }

        f32x4 accC[4] = {};
        f32x4 accR[4][2] = {};
#pragma unroll
        for (int rt = 0; rt < 4; ++rt)
#pragma unroll
            for (int kc = 0; kc < 2; ++kc) {
                accC[rt]    = MFMA16(qf[rt][kc], kf[kc],    accC[rt]);
                accR[rt][0] = MFMA16(qf[rt][kc], ef[0][kc], accR[rt][0]);
                accR[rt][1] = MFMA16(qf[rt][kc], ef[1][kc], accR[rt][1]);
            }
#pragma unroll
        for (int rt = 0; rt < 4; ++rt)
#pragma unroll
            for (int c = 0; c < 2; ++c)
#pragma unroll
                for (int r = 0; r < 4; ++r)
                    sR[(rt * 16 + fc * 4 + r) * 130 + (2 * w + c) * 16 + fr] = accR[rt][c][r];
        __syncthreads();
        const bool diag = (kt == qt);
#pragma unroll
        for (int rt = 0; rt < 4; ++rt)
#pragma unroll
            for (int r = 0; r < 4; ++r) {
                int qi = 16 * rt + 4 * fc + r;
                int kj = 16 * w + fr;
                float v = (accC[rt][r] + sR[qi * 130 + kj - qi + 63]) * SCL;
                if (!(diag && kj > qi)) sloc[rt * 4 + r] += EXP2(v);
            }
    }

    // ---- row-sum reduce: butterfly over fr lanes, then across waves ----
#pragma unroll
    for (int off = 1; off <= 8; off <<= 1)
#pragma unroll
        for (int i = 0; i < 16; ++i) sloc[i] += __shfl_xor(sloc[i], off, 64);
    __syncthreads();                                // phase-A reads done (sV alias safe)
    if (fr == 0)
#pragma unroll
        for (int i = 0; i < 16; ++i)
            sSt[(16 * (i >> 2) + 4 * fc + (i & 3)) * 4 + w] = sloc[i];
    __syncthreads();
    if (tid < 64)
        sInv[tid] = 1.0f / (sSt[tid * 4] + sSt[tid * 4 + 1] +
                            sSt[tid * 4 + 2] + sSt[tid * 4 + 3]);
    __syncthreads();
    float inv[16];
#pragma unroll
    for (int i = 0; i < 16; ++i) inv[i] = sInv[16 * (i >> 2) + 4 * fc + (i & 3)];

    // ================= PHASE B: probs + PV =================
    f32x4 accO[4] = {};
    ldK(0, kreg); ldE(0, ereg); ldV(0, vreg);
    for (int kt = 0; kt <= qt; ++kt) {
        const int k0 = 64 * kt;
        __syncthreads();                            // prev pa reads done; sInv read done
        wrK(kreg); wrE(ereg); wrV(vreg);
        __syncthreads();
        bf16x8 kf[2], ef[2][2], vf[2];
#pragma unroll
        for (int kc = 0; kc < 2; ++kc) {
            kf[kc] = *(const bf16x8*)(sK + (16 * w + fr) * 72 + kc * 32 + fc * 8);
            vf[kc] = *(const bf16x8*)(sV + (16 * w + fr) * 72 + kc * 32 + fc * 8);
        }
#pragma unroll
        for (int c = 0; c < 2; ++c)
#pragma unroll
            for (int kc = 0; kc < 2; ++kc)
                ef[c][kc] = *(const bf16x8*)(sE + ((2 * w + c) * 16 + fr) * 72 + kc * 32 + fc * 8);
        if (kt < qt) { ldK(k0 + 64, kreg); ldE(k0 + 64, ereg); ldV(k0 + 64, vreg); }

        f32x4 accC[4] = {};
        f32x4 accR[4][2] = {};
#pragma unroll
        for (int rt = 0; rt < 4; ++rt)
#pragma unroll
            for (int kc = 0; kc < 2; ++kc) {
                accC[rt]    = MFMA16(qf[rt][kc], kf[kc],    accC[rt]);
                accR[rt][0] = MFMA16(qf[rt][kc], ef[0][kc], accR[rt][0]);
                accR[rt][1] = MFMA16(qf[rt][kc], ef[1][kc], accR[rt][1]);
            }
#pragma unroll
        for (int rt = 0; rt < 4; ++rt)
#pragma unroll
            for (int c = 0; c < 2; ++c)
#pragma unroll
                for (int r = 0; r < 4; ++r)
                    sR[(rt * 16 + fc * 4 + r) * 130 + (2 * w + c) * 16 + fr] = accR[rt][c][r];
        __syncthreads();
        const bool diag = (kt == qt);
#pragma unroll
        for (int rt = 0; rt < 4; ++rt)
#pragma unroll
            for (int r = 0; r < 4; ++r) {
                int qi = 16 * rt + 4 * fc + r;
                int kj = 16 * w + fr;
                float v = (accC[rt][r] + sR[qi * 130 + kj - qi + 63]) * SCL;
                float p = (diag && kj > qi) ? 0.0f : EXP2(v) * inv[rt * 4 + r];
                Pout[((size_t)b * L_ + q0 + qi) * L_ + k0 + kj] = p;
                *(ushort*)(sPb + qi * 128 + SWZ(qi, 2 * kj)) = f2bf(p);
            }
        __syncthreads();
#pragma unroll
        for (int rt = 0; rt < 4; ++rt)
#pragma unroll
            for (int kc = 0; kc < 2; ++kc) {
                bf16x8 pa = *(const bf16x8*)(sPb + (16 * rt + fr) * 128 +
                                             SWZ(16 * rt + fr, kc * 64 + fc * 16));
                accO[rt] = MFMA16(pa, vf[kc], accO[rt]);
            }
    }

    // ---- zeros for the untouched upper region ----
    const int nz4 = 16 * (15 - qt);
    const f4 z = {0.0f, 0.0f, 0.0f, 0.0f};
#pragma unroll
    for (int i = 0; i < 4; ++i) {
        int row = rsub + 16 * i;
        float* base = Pout + ((size_t)b * L_ + q0 + row) * L_ + 64 * (qt + 1);
        for (int c = c4; c < nz4; c += 16) *(f4*)(base + 4 * c) = z;
    }
    // ---- O epilogue ----
#pragma unroll
    for (int rt = 0; rt < 4; ++rt)
#pragma unroll
        for (int rr = 0; rr < 4; ++rr)
            O[((size_t)b * L_ + q0 + rt * 16 + fc * 4 + rr) * D_ + 16 * w + fr] =
                accO[rt][rr];
}

// ---------------------------------------------------------------------------
extern "C" void kernel_launch(void* const* d_in, const int* in_sizes, int n_in,
                              void* d_out, int out_size, void* d_ws, size_t ws_size,
                              hipStream_t stream)
{
    const float* Q  = (const float*)d_in[0];
    const float* K  = (const float*)d_in[1];
    const float* V  = (const float*)d_in[2];
    const float* Er = (const float*)d_in[3];

    float* Out  = (float*)d_out;                          // [B, L, D]
    float* Attn = (float*)d_out + (size_t)B_ * L_ * D_;   // [B, L, L] probs

    pack_lin<<<2048, 256, 0, stream>>>(Q, K, Er, (char*)d_ws);
    pack_vt<<<dim3(16, B_), 256, 0, stream>>>(V, (char*)d_ws);
    fused_v5<<<dim3(B_, NQT), 256, 0, stream>>>((const char*)d_ws, Attn, Out);
}

// Round 6
// 183.124 us; speedup vs baseline: 1.6912x; 1.1491x over previous
//
#include <hip/hip_runtime.h>
#include <math.h>

#define B_ 64
#define L_ 1024
#define D_ 64
#define NQT 16
#define P_SH 84                        // shear row pad (f32): scatter/gather <=2-way

typedef float4 f4;
typedef __attribute__((ext_vector_type(8))) short bf16x8;
typedef __attribute__((ext_vector_type(4))) float f32x4;

#define MFMA16(a, b, c) __builtin_amdgcn_mfma_f32_16x16x32_bf16(a, b, c, 0, 0, 0)
#define EXP2(x) __builtin_amdgcn_exp2f(x)
#define SWZ(row, off) ((off) ^ ((((row) ^ ((row) >> 3)) & 7) << 4))
#define SCL 0.18033688011112042f       // log2(e) / TEMP

#define KB_OFF 0u
#define QB_OFF (8u << 20)
#define VT_OFF (16u << 20)
#define ER_OFF (24u << 20)

__device__ __forceinline__ ushort f2bf(float x) {
    unsigned u = __float_as_uint(x);
    return (ushort)((u + 0x7FFFu + ((u >> 16) & 1u)) >> 16);
}

// ---------------------------------------------------------------------------
// Prepack: Q,K,Er -> bf16 row-major; V -> bf16 transposed [b][d][l]
// ---------------------------------------------------------------------------
__global__ __launch_bounds__(256) void pack_lin(
    const float* __restrict__ Q, const float* __restrict__ K,
    const float* __restrict__ Er, char* __restrict__ ws)
{
    const int NQ = B_ * L_ * D_ / 4;
    const int NE = L_ * D_ / 4;
    ushort4* Qb = (ushort4*)(ws + QB_OFF);
    ushort4* Kb = (ushort4*)(ws + KB_OFF);
    ushort4* Eb = (ushort4*)(ws + ER_OFF);
    for (int i = blockIdx.x * 256 + threadIdx.x; i < 2 * NQ + NE;
         i += gridDim.x * 256) {
        const f4* src; ushort4* dst; int j;
        if (i < NQ)          { src = (const f4*)Q;  dst = Qb; j = i; }
        else if (i < 2 * NQ) { src = (const f4*)K;  dst = Kb; j = i - NQ; }
        else                 { src = (const f4*)Er; dst = Eb; j = i - 2 * NQ; }
        f4 v = src[j];
        dst[j] = make_ushort4(f2bf(v.x), f2bf(v.y), f2bf(v.z), f2bf(v.w));
    }
}

__global__ __launch_bounds__(256) void pack_vt(
    const float* __restrict__ V, char* __restrict__ ws)
{
    __shared__ float sT[64][68];
    ushort* VT = (ushort*)(ws + VT_OFF);
    const int lt = blockIdx.x, b = blockIdx.y;
    const int l0 = lt * 64;
    const int r = threadIdx.x >> 4, c4 = threadIdx.x & 15;
#pragma unroll
    for (int i = 0; i < 4; ++i) {
        int row = r + 16 * i;
        f4 v = *(const f4*)(V + ((size_t)b * L_ + l0 + row) * D_ + 4 * c4);
        sT[row][4 * c4 + 0] = v.x; sT[row][4 * c4 + 1] = v.y;
        sT[row][4 * c4 + 2] = v.z; sT[row][4 * c4 + 3] = v.w;
    }
    __syncthreads();
    const int d = threadIdx.x >> 2, seg = threadIdx.x & 3;
    ushort tmp[16];
#pragma unroll
    for (int j = 0; j < 16; ++j) tmp[j] = f2bf(sT[seg * 16 + j][d]);
    ushort* dst = VT + ((size_t)b * D_ + d) * L_ + l0 + seg * 16;
#pragma unroll
    for (int j = 0; j < 4; ++j) *(ushort4*)(dst + 4 * j) = *(ushort4*)(tmp + 4 * j);
}

// ---------------------------------------------------------------------------
// Fused kernel, wave-owns-16-q-rows decomposition:
//  - wave w handles q rows [q0+16w, q0+16w+16) x all 64 k-cols per tile
//  - skew shear + P->bf16 staging + row stats all wave-private (no barriers)
//  - 2 barriers/tile-iter (staging pair); prefetch issued a full iter early
// ---------------------------------------------------------------------------
__global__ __launch_bounds__(256, 2) void fused_v6(
    const char* __restrict__ ws, float* __restrict__ Pout, float* __restrict__ O)
{
    __shared__ __align__(16) ushort sK[64 * 72];          //  9216 B
    __shared__ __align__(16) ushort sE[128 * 72];         // 18432 B
    __shared__ __align__(16) ushort sV[64 * 72];          //  9216 B
    __shared__ __align__(16) float  sSh[4][16 * P_SH];    // 21504 B wave-private shear
    __shared__ __align__(16) char   sPb[4][2048];         //  8192 B wave-private P bf16

    const int tid = threadIdx.x;
    const int b = blockIdx.x;
    const int qt = 15 - (int)blockIdx.y;                  // heavy strips first
    const int q0 = qt * 64;
    const int lane = tid & 63, w = tid >> 6;
    const int fr = lane & 15, fc = lane >> 4;
    const int c4 = tid & 15, rsub = tid >> 4;
    const int t8 = tid >> 3, s8 = tid & 7;
    const int lb = (L_ - 64) - q0;

    const ushort* Kb = (const ushort*)(ws + KB_OFF) + (size_t)b * L_ * D_;
    const ushort* Qb = (const ushort*)(ws + QB_OFF) + (size_t)b * L_ * D_;
    const ushort* VT = (const ushort*)(ws + VT_OFF) + (size_t)b * D_ * L_;
    const ushort* Eb = (const ushort*)(ws + ER_OFF);

    float* sh = sSh[w];
    char*  pb = sPb[w];

    // Q fragments: wave's 16 rows, in registers for the whole kernel
    bf16x8 qf[2];
#pragma unroll
    for (int kc = 0; kc < 2; ++kc)
        qf[kc] = *(const bf16x8*)(Qb + (q0 + 16 * w + fr) * D_ + kc * 32 + fc * 8);

    auto ldK = [&](int k0, int4* r) {
        r[0] = *(const int4*)(Kb + (size_t)k0 * D_ + tid * 8);
        r[1] = *(const int4*)(Kb + (size_t)k0 * D_ + 2048 + tid * 8);
    };
    auto wrK = [&](const int4* r) {
        *(int4*)(sK + t8 * 72 + s8 * 8)        = r[0];
        *(int4*)(sK + (t8 + 32) * 72 + s8 * 8) = r[1];
    };
    auto ldE = [&](int k0, int4* r) {
#pragma unroll
        for (int j = 0; j < 4; ++j) {
            int l = lb + k0 + t8 + 32 * j;
            if (l > L_ - 1) l = L_ - 1;                   // clamp: masked entries only
            r[j] = *(const int4*)(Eb + (size_t)l * D_ + s8 * 8);
        }
    };
    auto wrE = [&](const int4* r) {
#pragma unroll
        for (int j = 0; j < 4; ++j)
            *(int4*)(sE + (t8 + 32 * j) * 72 + s8 * 8) = r[j];
    };
    auto ldV = [&](int k0, int4* r) {
#pragma unroll
        for (int j = 0; j < 2; ++j)
            r[j] = *(const int4*)(VT + (size_t)(t8 + 32 * j) * L_ + k0 + s8 * 8);
    };
    auto wrV = [&](const int4* r) {
#pragma unroll
        for (int j = 0; j < 2; ++j)
            *(int4*)(sV + (t8 + 32 * j) * 72 + s8 * 8) = r[j];
    };

    const int ebase = 48 - 16 * w;       // E LDS row base for this wave's frags

    float sA[4] = {0.0f, 0.0f, 0.0f, 0.0f};
    int4 kreg[2], ereg[4], vreg[2];

    // ================= PHASE A: per-row sums of 2^(score*log2e) =============
    ldK(0, kreg); ldE(0, ereg);
    for (int kt = 0; kt <= qt; ++kt) {
        __syncthreads();                 // WAR on staging; drains prefetch vmcnt
        wrK(kreg); wrE(ereg);
        __syncthreads();                 // staging visible

        f32x4 accC[4] = {};
        f32x4 accR[5] = {};
        {
            bf16x8 kf[4][2];
#pragma unroll
            for (int a = 0; a < 4; ++a)
#pragma unroll
                for (int kc = 0; kc < 2; ++kc)
                    kf[a][kc] = *(const bf16x8*)(sK + (16 * a + fr) * 72 + kc * 32 + fc * 8);
            bf16x8 ef[5][2];
#pragma unroll
            for (int cc = 0; cc < 5; ++cc)
#pragma unroll
                for (int kc = 0; kc < 2; ++kc)
                    ef[cc][kc] = *(const bf16x8*)(sE + (ebase + 16 * cc + fr) * 72 + kc * 32 + fc * 8);
            if (kt < qt) { ldK(64 * (kt + 1), kreg); ldE(64 * (kt + 1), ereg); }
#pragma unroll
            for (int a = 0; a < 4; ++a)
#pragma unroll
                for (int kc = 0; kc < 2; ++kc)
                    accC[a] = MFMA16(qf[kc], kf[a][kc], accC[a]);
#pragma unroll
            for (int cc = 0; cc < 5; ++cc)
#pragma unroll
                for (int kc = 0; kc < 2; ++kc)
                    accR[cc] = MFMA16(qf[kc], ef[cc][kc], accR[cc]);
        }
        // wave-private shear: scatter R[qi][twl], gather twl = kj - qi + 15
#pragma unroll
        for (int cc = 0; cc < 5; ++cc)
#pragma unroll
            for (int r = 0; r < 4; ++r)
                sh[(4 * fc + r) * P_SH + 16 * cc + fr] = accR[cc][r];
        const bool diag = (kt == qt);
#pragma unroll
        for (int a = 0; a < 4; ++a)
#pragma unroll
            for (int r = 0; r < 4; ++r) {
                int qi = 4 * fc + r;
                int kj = fr + 16 * a;
                float v = (accC[a][r] + sh[qi * P_SH + kj - qi + 15]) * SCL;
                if (!(diag && kj > 16 * w + qi)) sA[r] += EXP2(v);
            }
    }
    // wave-local row-sum reduce over the 16 fr-lanes
    float inv[4];
#pragma unroll
    for (int r = 0; r < 4; ++r) {
        float s = sA[r];
#pragma unroll
        for (int off = 1; off <= 8; off <<= 1) s += __shfl_xor(s, off, 64);
        inv[r] = 1.0f / s;
    }

    // ================= PHASE B: probs + PV ==================================
    f32x4 accO[4] = {};
    ldK(0, kreg); ldE(0, ereg); ldV(0, vreg);
    for (int kt = 0; kt <= qt; ++kt) {
        const int k0 = 64 * kt;
        __syncthreads();
        wrK(kreg); wrE(ereg); wrV(vreg);
        __syncthreads();

        f32x4 accC[4] = {};
        f32x4 accR[5] = {};
        bf16x8 vf[4][2];
        {
            bf16x8 kf[4][2];
#pragma unroll
            for (int a = 0; a < 4; ++a)
#pragma unroll
                for (int kc = 0; kc < 2; ++kc)
                    kf[a][kc] = *(const bf16x8*)(sK + (16 * a + fr) * 72 + kc * 32 + fc * 8);
            bf16x8 ef[5][2];
#pragma unroll
            for (int cc = 0; cc < 5; ++cc)
#pragma unroll
                for (int kc = 0; kc < 2; ++kc)
                    ef[cc][kc] = *(const bf16x8*)(sE + (ebase + 16 * cc + fr) * 72 + kc * 32 + fc * 8);
#pragma unroll
            for (int dd = 0; dd < 4; ++dd)
#pragma unroll
                for (int kc = 0; kc < 2; ++kc)
                    vf[dd][kc] = *(const bf16x8*)(sV + (16 * dd + fr) * 72 + kc * 32 + fc * 8);
            if (kt < qt) { ldK(k0 + 64, kreg); ldE(k0 + 64, ereg); ldV(k0 + 64, vreg); }
#pragma unroll
            for (int a = 0; a < 4; ++a)
#pragma unroll
                for (int kc = 0; kc < 2; ++kc)
                    accC[a] = MFMA16(qf[kc], kf[a][kc], accC[a]);
#pragma unroll
            for (int cc = 0; cc < 5; ++cc)
#pragma unroll
                for (int kc = 0; kc < 2; ++kc)
                    accR[cc] = MFMA16(qf[kc], ef[cc][kc], accR[cc]);
        }
#pragma unroll
        for (int cc = 0; cc < 5; ++cc)
#pragma unroll
            for (int r = 0; r < 4; ++r)
                sh[(4 * fc + r) * P_SH + 16 * cc + fr] = accR[cc][r];
        const bool diag = (kt == qt);
#pragma unroll
        for (int a = 0; a < 4; ++a)
#pragma unroll
            for (int r = 0; r < 4; ++r) {
                int qi = 4 * fc + r;
                int kj = fr + 16 * a;
                float v = (accC[a][r] + sh[qi * P_SH + kj - qi + 15]) * SCL;
                float p = (diag && kj > 16 * w + qi) ? 0.0f : EXP2(v) * inv[r];
                Pout[((size_t)b * L_ + q0 + 16 * w + qi) * L_ + k0 + kj] = p;
                *(ushort*)(pb + qi * 128 + SWZ(qi, 2 * kj)) = f2bf(p);
            }
        // PV: wave-private pa read (in-wave ordering, no barrier)
#pragma unroll
        for (int kc = 0; kc < 2; ++kc) {
            bf16x8 pa = *(const bf16x8*)(pb + fr * 128 + SWZ(fr, kc * 64 + fc * 16));
#pragma unroll
            for (int dd = 0; dd < 4; ++dd)
                accO[dd] = MFMA16(pa, vf[dd][kc], accO[dd]);
        }
    }

    // ---- zeros for the untouched upper region ----
    const int nz4 = 16 * (15 - qt);
    const f4 z = {0.0f, 0.0f, 0.0f, 0.0f};
#pragma unroll
    for (int i = 0; i < 4; ++i) {
        int row = rsub + 16 * i;
        float* base = Pout + ((size_t)b * L_ + q0 + row) * L_ + 64 * (qt + 1);
        for (int c = c4; c < nz4; c += 16) *(f4*)(base + 4 * c) = z;
    }
    // ---- O epilogue ----
#pragma unroll
    for (int dd = 0; dd < 4; ++dd)
#pragma unroll
        for (int r = 0; r < 4; ++r)
            O[((size_t)b * L_ + q0 + 16 * w + 4 * fc + r) * D_ + 16 * dd + fr] =
                accO[dd][r];
}

// ---------------------------------------------------------------------------
extern "C" void kernel_launch(void* const* d_in, const int* in_sizes, int n_in,
                              void* d_out, int out_size, void* d_ws, size_t ws_size,
                              hipStream_t stream)
{
    const float* Q  = (const float*)d_in[0];
    const float* K  = (const float*)d_in[1];
    const float* V  = (const float*)d_in[2];
    const float* Er = (const float*)d_in[3];

    float* Out  = (float*)d_out;                          // [B, L, D]
    float* Attn = (float*)d_out + (size_t)B_ * L_ * D_;   // [B, L, L] probs

    pack_lin<<<2048, 256, 0, stream>>>(Q, K, Er, (char*)d_ws);
    pack_vt<<<dim3(16, B_), 256, 0, stream>>>(V, (char*)d_ws);
    fused_v6<<<dim3(B_, NQT), 256, 0, stream>>>((const char*)d_ws, Attn, Out);
}